// Round 15
// baseline (1007.083 us; speedup 1.0000x reference)
//
#include <hip/hip_runtime.h>

typedef float  f4v __attribute__((ext_vector_type(4)));
typedef short  s8v __attribute__((ext_vector_type(8)));

#define B_   64
#define L_   128
#define T_   255
#define RMAX 127
#define BPK_HALF 5242880   // shorts per half (5120*1024)

__device__ __forceinline__ unsigned short f2bf(float f) {
    union { float f; unsigned int u; } v; v.f = f;
    unsigned int u = v.u;
    unsigned int r = u + 0x7fffu + ((u >> 16) & 1u);
    return (unsigned short)(r >> 16);
}
__device__ __forceinline__ float bf2f(unsigned short s) {
    union { unsigned int u; float f; } v; v.u = ((unsigned int)s) << 16;
    return v.f;
}
__device__ __forceinline__ float sigf(float x) { return 1.f / (1.f + expf(-x)); }

// ---------------- conversion ----------------
__global__ void k_cvt_bf16(const float* __restrict__ in, unsigned short* __restrict__ out, long n4) {
    long i = blockIdx.x * (long)blockDim.x + threadIdx.x;
    if (i >= n4) return;
    float4 v = ((const float4*)in)[i];
    ushort4 o;
    o.x = f2bf(v.x); o.y = f2bf(v.y); o.z = f2bf(v.z); o.w = f2bf(v.w);
    ((ushort4*)out)[i] = o;
}

// in [K][N] fp32 -> out [N][K] bf16
__global__ void k_transpose_bf16(const float* __restrict__ in, unsigned short* __restrict__ out, int K, int N) {
    __shared__ float tile[32][33];
    int n0 = blockIdx.x * 32, k0 = blockIdx.y * 32;
    int tx = threadIdx.x, ty = threadIdx.y;   // 32 x 8
    for (int i = ty; i < 32; i += 8) tile[i][tx] = in[(size_t)(k0 + i) * N + n0 + tx];
    __syncthreads();
    for (int i = ty; i < 32; i += 8) out[(size_t)(n0 + i) * K + k0 + tx] = f2bf(tile[tx][i]);
}

// ---------------- pack Wr into MFMA-fragment order ----------------
__global__ void k_pack_b(const unsigned short* __restrict__ wrt, unsigned short* __restrict__ bpk) {
    int u = blockIdx.x * 256 + threadIdx.x;        // [0, 1310720)
    int half = u / 655360;
    int v = u % 655360;
    int cg = v / 10240;
    int rem = v % 10240;
    int g = rem / 2048;
    int rem2 = rem % 2048;
    int kk = rem2 >> 6, lane = rem2 & 63;
    int col = g * 1024 + cg * 16 + (lane & 15);
    int kb = kk * 32 + (lane >> 4) * 8;
    s8v val = *(const s8v*)(wrt + (size_t)col * 2048 + half * 1024 + kb);
    *(s8v*)(bpk + (size_t)u * 8) = val;
}

// ---------------- control ----------------
__global__ void k_control(const int* __restrict__ tr, int* __restrict__ desc) {
    if (threadIdx.x != 0 || blockIdx.x != 0) return;
    int stack[140];
    int sp = 0, bp = 0, r = 0;
    for (int t = 0; t < T_; ++t) {
        int a = tr[t];
        if (a == 1) {
            if (bp < L_) { stack[sp++] = bp; bp++; }
        } else if (a == 2) {
            if (sp >= 2) {
                int right = stack[sp - 1], left = stack[sp - 2];
                sp -= 2;
                desc[2 + r] = left;
                desc[2 + RMAX + r] = right;
                stack[sp++] = -(r + 1);
                r++;
            }
        }
    }
    desc[0] = r;
    desc[1] = (sp > 0) ? stack[sp - 1] : 0;
}

// ---------------- word projection: 128x128 tile, BK=64, A from bf16 sb ----------------
__global__ __launch_bounds__(256) void k_proj2(const unsigned short* __restrict__ sb,
                                               const unsigned short* __restrict__ wwt,
                                               const float* __restrict__ bw,
                                               unsigned short* __restrict__ hw,
                                               float* __restrict__ cw) {
    __shared__ unsigned short lA[128 * 64];
    __shared__ unsigned short lB[128 * 64];
    int tid = threadIdx.x, wv = tid >> 6, lane = tid & 63;
    int lr = lane & 15, lq = lane >> 4;
    int wr = wv >> 1, wc = wv & 1;
    int rb = blockIdx.y * 128, cb = blockIdx.x * 128;
    f4v acc[4][4];
    #pragma unroll
    for (int i = 0; i < 4; ++i)
        #pragma unroll
        for (int j = 0; j < 4; ++j) acc[i][j] = (f4v){0.f, 0.f, 0.f, 0.f};

    for (int ks = 0; ks < 1024; ks += 64) {
        #pragma unroll
        for (int t = 0; t < 4; ++t) {
            int p = t * 256 + tid;
            int row = p >> 3, kgs = p & 7, kg = kgs ^ (row & 7);
            *(s8v*)(lA + (size_t)p * 8) = *(const s8v*)(sb  + (size_t)(rb + row) * 1024 + ks + kg * 8);
            *(s8v*)(lB + (size_t)p * 8) = *(const s8v*)(wwt + (size_t)(cb + row) * 1024 + ks + kg * 8);
        }
        __syncthreads();
        #pragma unroll
        for (int s = 0; s < 2; ++s) {
            int kgx = (s * 4 + lq) ^ (lr & 7);
            s8v a[4], b[4];
            #pragma unroll
            for (int i = 0; i < 4; ++i) {
                int rowa = wr * 64 + i * 16 + lr;
                int rowb = wc * 64 + i * 16 + lr;
                a[i] = *(const s8v*)(lA + (size_t)(rowa * 8 + kgx) * 8);
                b[i] = *(const s8v*)(lB + (size_t)(rowb * 8 + kgx) * 8);
            }
            #pragma unroll
            for (int i = 0; i < 4; ++i)
                #pragma unroll
                for (int j = 0; j < 4; ++j)
                    acc[i][j] = __builtin_amdgcn_mfma_f32_16x16x32_bf16(a[i], b[j], acc[i][j], 0, 0, 0);
        }
        __syncthreads();
    }
    bool isH = (cb < 1024);
    #pragma unroll
    for (int j = 0; j < 4; ++j) {
        int col = cb + wc * 64 + j * 16 + lr;
        float bias = bw[col];
        #pragma unroll
        for (int i = 0; i < 4; ++i) {
            #pragma unroll
            for (int jj = 0; jj < 4; ++jj) {
                int m = rb + wr * 64 + i * 16 + lq * 4 + jj;
                float v = acc[i][j][jj] + bias;
                if (isH) hw[(size_t)m * 1024 + col] = f2bf(v);
                else     cw[(size_t)m * 1024 + (col - 1024)] = v;
            }
        }
    }
}

// ---------------- PW precompute (round-5/11 proven simple form) ----------------
__global__ __launch_bounds__(256) void k_pw(const int* __restrict__ desc,
                                            const unsigned short* __restrict__ hw,
                                            const unsigned short* __restrict__ wrt,
                                            const float* __restrict__ br,
                                            unsigned short* __restrict__ pwb) {
    __shared__ unsigned short lA[128 * 64];
    __shared__ unsigned short lB[128 * 64];
    int tid = threadIdx.x, wv = tid >> 6, lane = tid & 63;
    int lr = lane & 15, lq = lane >> 4;
    int wr = wv >> 1, wc = wv & 1;
    int cb = blockIdx.x * 128;
    int r0 = blockIdx.y * 2;
    int nred = desc[0];
    int s0[2], s1[2];
    s0[0] = (r0 < nred) ? desc[2 + r0] : -1;
    s0[1] = (r0 < nred) ? desc[2 + RMAX + r0] : -1;
    s1[0] = (r0 + 1 < nred) ? desc[2 + r0 + 1] : -1;
    s1[1] = (r0 + 1 < nred) ? desc[2 + RMAX + r0 + 1] : -1;
    bool need[2];
    need[0] = (s0[0] >= 0) || (s1[0] >= 0);
    need[1] = (s0[1] >= 0) || (s1[1] >= 0);

    f4v acc[4][4];
    #pragma unroll
    for (int i = 0; i < 4; ++i)
        #pragma unroll
        for (int j = 0; j < 4; ++j) acc[i][j] = (f4v){0.f, 0.f, 0.f, 0.f};

    for (int c = 0; c < 32; ++c) {
        int side = c >> 4;
        if (!need[side]) continue;
        int kloc = (c & 15) * 64;
        #pragma unroll
        for (int t = 0; t < 4; ++t) {
            int p = t * 256 + tid;
            int row = p >> 3, kgs = p & 7, kg = kgs ^ (row & 7);
            int m = row & 63;
            int src = (row >> 6) ? s1[side] : s0[side];
            s8v va = (s8v){0,0,0,0,0,0,0,0};
            if (src >= 0)
                va = *(const s8v*)(hw + (size_t)(m * L_ + src) * 1024 + kloc + kg * 8);
            *(s8v*)(lA + (size_t)p * 8) = va;
            *(s8v*)(lB + (size_t)p * 8) = *(const s8v*)(wrt + (size_t)(cb + row) * 2048 + side * 1024 + kloc + kg * 8);
        }
        __syncthreads();
        #pragma unroll
        for (int s = 0; s < 2; ++s) {
            int kgx = (s * 4 + lq) ^ (lr & 7);
            s8v a[4], b[4];
            #pragma unroll
            for (int i = 0; i < 4; ++i) {
                int rowa = wr * 64 + i * 16 + lr;
                int rowb = wc * 64 + i * 16 + lr;
                a[i] = *(const s8v*)(lA + (size_t)(rowa * 8 + kgx) * 8);
                b[i] = *(const s8v*)(lB + (size_t)(rowb * 8 + kgx) * 8);
            }
            #pragma unroll
            for (int i = 0; i < 4; ++i)
                #pragma unroll
                for (int j = 0; j < 4; ++j)
                    acc[i][j] = __builtin_amdgcn_mfma_f32_16x16x32_bf16(a[i], b[j], acc[i][j], 0, 0, 0);
        }
        __syncthreads();
    }
    #pragma unroll
    for (int j = 0; j < 4; ++j) {
        int col = cb + wc * 64 + j * 16 + lr;
        float bias = br[col];
        #pragma unroll
        for (int i = 0; i < 4; ++i) {
            #pragma unroll
            for (int jj = 0; jj < 4; ++jj) {
                int prow = wr * 64 + i * 16 + lq * 4 + jj;
                int rr = r0 + (prow >> 6), m = prow & 63;
                if (rr < nred)
                    pwb[((size_t)rr * B_ + m) * 5120 + col] = f2bf(acc[i][j][jj] + bias);
            }
        }
    }
}

// ---------------- one reduce step: 256 blocks x 1024 thr (16 waves = K-split 16 -> 4 waves/SIMD) ----------------
// cg = (bid&7)*8 + ((bid>>3)&7), rh = bid>>6. Block: 16 rows x 16 ch x 5 gates.
__global__ __launch_bounds__(1024, 1) void k_step(const int* __restrict__ desc,
                                                  const float* __restrict__ cw,
                                                  const unsigned short* __restrict__ bpk,
                                                  const unsigned short* __restrict__ pwb,
                                                  unsigned short* __restrict__ hpk,
                                                  float* __restrict__ nc,
                                                  int r) {
    int nred = desc[0];
    if (r >= nred) return;
    int ls = desc[2 + r], rs = desc[2 + RMAX + r];
    __shared__ float scr[16 * 5 * 16 * 17];    // 87040 B
    int tid = threadIdx.x, kq = tid >> 6, lane = tid & 63;
    int bid = blockIdx.x;
    int cg = (bid & 7) * 8 + ((bid >> 3) & 7);
    int rh = bid >> 6;
    int lq = lane >> 4;

    // epilogue prefetch (waves 0-3 only)
    int m_e = (tid & 255) >> 4, ci_e = tid & 15;
    int mg_e = rh * 16 + m_e, chh_e = cg * 16 + ci_e;
    float pw_pre[5] = {0.f, 0.f, 0.f, 0.f, 0.f};
    float lc = 0.f, rc = 0.f;
    if (tid < 256) {
        #pragma unroll
        for (int g = 0; g < 5; ++g)
            pw_pre[g] = bf2f(__builtin_nontemporal_load(&pwb[((size_t)r * B_ + mg_e) * 5120 + g * 1024 + chh_e]));
        lc = (ls >= 0) ? __builtin_nontemporal_load(&cw[(size_t)(mg_e * L_ + ls) * 1024 + chh_e])
                       : __builtin_nontemporal_load(&nc[((size_t)(-1 - ls) * B_ + mg_e) * 1024 + chh_e]);
        rc = (rs >= 0) ? __builtin_nontemporal_load(&cw[(size_t)(mg_e * L_ + rs) * 1024 + chh_e])
                       : __builtin_nontemporal_load(&nc[((size_t)(-1 - rs) * B_ + mg_e) * 1024 + chh_e]);
    }

    f4v acc[5];
    #pragma unroll
    for (int g = 0; g < 5; ++g) acc[g] = (f4v){0.f, 0.f, 0.f, 0.f};

    #pragma unroll
    for (int side = 0; side < 2; ++side) {
        int src = side ? rs : ls;
        if (src >= 0) continue;                 // word side fully handled by PW
        const unsigned short* A = hpk + (size_t)(-1 - src) * 65536;
        const unsigned short* Bb = bpk + (size_t)side * BPK_HALF;
        #pragma unroll
        for (int kki = 0; kki < 2; ++kki) {
            int kk = kq * 2 + kki;
            s8v a = *(const s8v*)(A + (size_t)((rh * 32 + kk) * 64 + lane) * 8);
            #pragma unroll
            for (int g = 0; g < 5; ++g) {
                s8v b = *(const s8v*)(Bb + (size_t)((((size_t)cg * 5 + g) * 32 + kk) * 64 + lane) * 8);
                acc[g] = __builtin_amdgcn_mfma_f32_16x16x32_bf16(a, b, acc[g], 0, 0, 0);
            }
        }
    }
    // write K-split partials
    #pragma unroll
    for (int g = 0; g < 5; ++g)
        #pragma unroll
        for (int jj = 0; jj < 4; ++jj)
            scr[((kq * 5 + g) * 16 + lq * 4 + jj) * 17 + (lane & 15)] = acc[g][jj];
    __syncthreads();
    if (tid < 256) {
        float gg[5];
        #pragma unroll
        for (int g = 0; g < 5; ++g) {
            float s = pw_pre[g];
            #pragma unroll
            for (int q = 0; q < 16; ++q) s += scr[((q * 5 + g) * 16 + m_e) * 17 + ci_e];
            gg[g] = s;
        }
        float cn = sigf(gg[1]) * lc + sigf(gg[2]) * rc + sigf(gg[0]) * tanhf(gg[4]);
        float hn = sigf(gg[3]) * tanhf(cn);
        unsigned short hb = f2bf(hn);
        __builtin_nontemporal_store(cn, &nc[((size_t)r * B_ + mg_e) * 1024 + chh_e]);
        // packed-A write for future steps (also serves k_final)
        int rf = mg_e >> 4, lr2 = mg_e & 15, kk2 = chh_e >> 5, lq2 = (chh_e >> 3) & 3, j = chh_e & 7;
        __builtin_nontemporal_store(hb, &hpk[(size_t)r * 65536 + (size_t)((rf * 32 + kk2) * 64 + lq2 * 16 + lr2) * 8 + j]);
    }
}

// ---------------- final: read from hw (word) or fragment-packed hpk (node) ----------------
__global__ void k_final(const int* __restrict__ desc,
                        const unsigned short* __restrict__ hw,
                        const unsigned short* __restrict__ hpk,
                        float* __restrict__ out) {
    int idx = blockIdx.x * 256 + threadIdx.x;
    if (idx >= B_ * 1024) return;
    int m = idx >> 10, ch = idx & 1023;
    int fs = desc[1];
    unsigned short v;
    if (fs >= 0) {
        v = hw[((size_t)(m * L_ + fs) << 10) + ch];
    } else {
        int r = -1 - fs;
        int rf = m >> 4, lr2 = m & 15, kk2 = ch >> 5, lq2 = (ch >> 3) & 3, j = ch & 7;
        v = hpk[(size_t)r * 65536 + (size_t)((rf * 32 + kk2) * 64 + lq2 * 16 + lr2) * 8 + j];
    }
    out[idx] = bf2f(v);
}

extern "C" void kernel_launch(void* const* d_in, const int* in_sizes, int n_in,
                              void* d_out, int out_size, void* d_ws, size_t ws_size,
                              hipStream_t stream) {
    const float* sentence = (const float*)d_in[0];
    const int*   trans    = (const int*)d_in[1];
    const float* Ww       = (const float*)d_in[2];
    const float* bw       = (const float*)d_in[3];
    const float* Wr       = (const float*)d_in[4];
    const float* br       = (const float*)d_in[5];
    float* out = (float*)d_out;

    char* w = (char*)d_ws;
    size_t off = 0;
    unsigned short* Wrt = (unsigned short*)(w + off); off += (size_t)5120 * 2048 * 2;      // 21.0 MB
    unsigned short* Wwt = (unsigned short*)(w + off); off += (size_t)2048 * 1024 * 2;      //  4.2 MB
    unsigned short* bpk = (unsigned short*)(w + off); off += (size_t)2 * BPK_HALF * 2;     // 21.0 MB
    unsigned short* sb  = (unsigned short*)(w + off); off += (size_t)8192 * 1024 * 2;      // 16.8 MB
    unsigned short* hw  = (unsigned short*)(w + off); off += (size_t)8192 * 1024 * 2;      // 16.8 MB
    float*          cw  = (float*)(w + off);          off += (size_t)8192 * 1024 * 4;      // 33.6 MB
    float*          nc  = (float*)(w + off);          off += (size_t)RMAX * B_ * 1024 * 4; // 33.3 MB
    unsigned short* hpk = (unsigned short*)(w + off); off += (size_t)RMAX * 65536 * 2;     // 16.6 MB
    unsigned short* pwb = (unsigned short*)(w + off); off += (size_t)RMAX * B_ * 5120 * 2; // 83.2 MB
    int*            desc = (int*)(w + off);           off += 1024;                         // ~246.5 MB

    {
        long n4 = (long)8192 * 1024 / 4;
        k_cvt_bf16<<<dim3((unsigned)((n4 + 255) / 256)), dim3(256), 0, stream>>>(sentence, sb, n4);
    }
    k_transpose_bf16<<<dim3(2048 / 32, 1024 / 32), dim3(32, 8), 0, stream>>>(Ww, Wwt, 1024, 2048);
    k_transpose_bf16<<<dim3(5120 / 32, 2048 / 32), dim3(32, 8), 0, stream>>>(Wr, Wrt, 2048, 5120);
    k_pack_b<<<dim3(5120), dim3(256), 0, stream>>>(Wrt, bpk);
    k_control<<<dim3(1), dim3(1), 0, stream>>>(trans, desc);
    k_proj2<<<dim3(16, 64), dim3(256), 0, stream>>>(sb, Wwt, bw, hw, cw);
    k_pw<<<dim3(40, 64), dim3(256), 0, stream>>>(desc, hw, Wrt, br, pwb);
    for (int r = 0; r < RMAX; ++r)
        k_step<<<dim3(256), dim3(1024), 0, stream>>>(desc, cw, bpk, pwb, hpk, nc, r);
    k_final<<<dim3((B_ * 1024 + 255) / 256), dim3(256), 0, stream>>>(desc, hw, hpk, out);
}

// Round 16
// 980.383 us; speedup vs baseline: 1.0272x; 1.0272x over previous
//
#include <hip/hip_runtime.h>

typedef float  f4v __attribute__((ext_vector_type(4)));
typedef short  s8v __attribute__((ext_vector_type(8)));

#define B_   64
#define L_   128
#define T_   255
#define RMAX 127
#define BPK_HALF 5242880   // shorts per half (5120*1024)

__device__ __forceinline__ unsigned short f2bf(float f) {
    union { float f; unsigned int u; } v; v.f = f;
    unsigned int u = v.u;
    unsigned int r = u + 0x7fffu + ((u >> 16) & 1u);
    return (unsigned short)(r >> 16);
}
__device__ __forceinline__ float bf2f(unsigned short s) {
    union { unsigned int u; float f; } v; v.u = ((unsigned int)s) << 16;
    return v.f;
}
__device__ __forceinline__ float sigf(float x) { return 1.f / (1.f + expf(-x)); }

// ---------------- conversion ----------------
__global__ void k_cvt_bf16(const float* __restrict__ in, unsigned short* __restrict__ out, long n4) {
    long i = blockIdx.x * (long)blockDim.x + threadIdx.x;
    if (i >= n4) return;
    float4 v = ((const float4*)in)[i];
    ushort4 o;
    o.x = f2bf(v.x); o.y = f2bf(v.y); o.z = f2bf(v.z); o.w = f2bf(v.w);
    ((ushort4*)out)[i] = o;
}

// in [K][N] fp32 -> out [N][K] bf16
__global__ void k_transpose_bf16(const float* __restrict__ in, unsigned short* __restrict__ out, int K, int N) {
    __shared__ float tile[32][33];
    int n0 = blockIdx.x * 32, k0 = blockIdx.y * 32;
    int tx = threadIdx.x, ty = threadIdx.y;   // 32 x 8
    for (int i = ty; i < 32; i += 8) tile[i][tx] = in[(size_t)(k0 + i) * N + n0 + tx];
    __syncthreads();
    for (int i = ty; i < 32; i += 8) out[(size_t)(n0 + i) * K + k0 + tx] = f2bf(tile[tx][i]);
}

// ---------------- pack Wr into MFMA-fragment order ----------------
__global__ void k_pack_b(const unsigned short* __restrict__ wrt, unsigned short* __restrict__ bpk) {
    int u = blockIdx.x * 256 + threadIdx.x;        // [0, 1310720)
    int half = u / 655360;
    int v = u % 655360;
    int cg = v / 10240;
    int rem = v % 10240;
    int g = rem / 2048;
    int rem2 = rem % 2048;
    int kk = rem2 >> 6, lane = rem2 & 63;
    int col = g * 1024 + cg * 16 + (lane & 15);
    int kb = kk * 32 + (lane >> 4) * 8;
    s8v val = *(const s8v*)(wrt + (size_t)col * 2048 + half * 1024 + kb);
    *(s8v*)(bpk + (size_t)u * 8) = val;
}

// ---------------- control ----------------
__global__ void k_control(const int* __restrict__ tr, int* __restrict__ desc) {
    if (threadIdx.x != 0 || blockIdx.x != 0) return;
    int stack[140];
    int sp = 0, bp = 0, r = 0;
    for (int t = 0; t < T_; ++t) {
        int a = tr[t];
        if (a == 1) {
            if (bp < L_) { stack[sp++] = bp; bp++; }
        } else if (a == 2) {
            if (sp >= 2) {
                int right = stack[sp - 1], left = stack[sp - 2];
                sp -= 2;
                desc[2 + r] = left;
                desc[2 + RMAX + r] = right;
                stack[sp++] = -(r + 1);
                r++;
            }
        }
    }
    desc[0] = r;
    desc[1] = (sp > 0) ? stack[sp - 1] : 0;
}

// ---------------- word projection: 128x128 tile, BK=64, A from bf16 sb ----------------
__global__ __launch_bounds__(256) void k_proj2(const unsigned short* __restrict__ sb,
                                               const unsigned short* __restrict__ wwt,
                                               const float* __restrict__ bw,
                                               unsigned short* __restrict__ hw,
                                               float* __restrict__ cw) {
    __shared__ unsigned short lA[128 * 64];
    __shared__ unsigned short lB[128 * 64];
    int tid = threadIdx.x, wv = tid >> 6, lane = tid & 63;
    int lr = lane & 15, lq = lane >> 4;
    int wr = wv >> 1, wc = wv & 1;
    int rb = blockIdx.y * 128, cb = blockIdx.x * 128;
    f4v acc[4][4];
    #pragma unroll
    for (int i = 0; i < 4; ++i)
        #pragma unroll
        for (int j = 0; j < 4; ++j) acc[i][j] = (f4v){0.f, 0.f, 0.f, 0.f};

    for (int ks = 0; ks < 1024; ks += 64) {
        #pragma unroll
        for (int t = 0; t < 4; ++t) {
            int p = t * 256 + tid;
            int row = p >> 3, kgs = p & 7, kg = kgs ^ (row & 7);
            *(s8v*)(lA + (size_t)p * 8) = *(const s8v*)(sb  + (size_t)(rb + row) * 1024 + ks + kg * 8);
            *(s8v*)(lB + (size_t)p * 8) = *(const s8v*)(wwt + (size_t)(cb + row) * 1024 + ks + kg * 8);
        }
        __syncthreads();
        #pragma unroll
        for (int s = 0; s < 2; ++s) {
            int kgx = (s * 4 + lq) ^ (lr & 7);
            s8v a[4], b[4];
            #pragma unroll
            for (int i = 0; i < 4; ++i) {
                int rowa = wr * 64 + i * 16 + lr;
                int rowb = wc * 64 + i * 16 + lr;
                a[i] = *(const s8v*)(lA + (size_t)(rowa * 8 + kgx) * 8);
                b[i] = *(const s8v*)(lB + (size_t)(rowb * 8 + kgx) * 8);
            }
            #pragma unroll
            for (int i = 0; i < 4; ++i)
                #pragma unroll
                for (int j = 0; j < 4; ++j)
                    acc[i][j] = __builtin_amdgcn_mfma_f32_16x16x32_bf16(a[i], b[j], acc[i][j], 0, 0, 0);
        }
        __syncthreads();
    }
    bool isH = (cb < 1024);
    #pragma unroll
    for (int j = 0; j < 4; ++j) {
        int col = cb + wc * 64 + j * 16 + lr;
        float bias = bw[col];
        #pragma unroll
        for (int i = 0; i < 4; ++i) {
            #pragma unroll
            for (int jj = 0; jj < 4; ++jj) {
                int m = rb + wr * 64 + i * 16 + lq * 4 + jj;
                float v = acc[i][j][jj] + bias;
                if (isH) hw[(size_t)m * 1024 + col] = f2bf(v);
                else     cw[(size_t)m * 1024 + (col - 1024)] = v;
            }
        }
    }
}

// ---------------- PW precompute (round-5/11 proven simple form) ----------------
__global__ __launch_bounds__(256) void k_pw(const int* __restrict__ desc,
                                            const unsigned short* __restrict__ hw,
                                            const unsigned short* __restrict__ wrt,
                                            const float* __restrict__ br,
                                            unsigned short* __restrict__ pwb) {
    __shared__ unsigned short lA[128 * 64];
    __shared__ unsigned short lB[128 * 64];
    int tid = threadIdx.x, wv = tid >> 6, lane = tid & 63;
    int lr = lane & 15, lq = lane >> 4;
    int wr = wv >> 1, wc = wv & 1;
    int cb = blockIdx.x * 128;
    int r0 = blockIdx.y * 2;
    int nred = desc[0];
    int s0[2], s1[2];
    s0[0] = (r0 < nred) ? desc[2 + r0] : -1;
    s0[1] = (r0 < nred) ? desc[2 + RMAX + r0] : -1;
    s1[0] = (r0 + 1 < nred) ? desc[2 + r0 + 1] : -1;
    s1[1] = (r0 + 1 < nred) ? desc[2 + RMAX + r0 + 1] : -1;
    bool need[2];
    need[0] = (s0[0] >= 0) || (s1[0] >= 0);
    need[1] = (s0[1] >= 0) || (s1[1] >= 0);

    f4v acc[4][4];
    #pragma unroll
    for (int i = 0; i < 4; ++i)
        #pragma unroll
        for (int j = 0; j < 4; ++j) acc[i][j] = (f4v){0.f, 0.f, 0.f, 0.f};

    for (int c = 0; c < 32; ++c) {
        int side = c >> 4;
        if (!need[side]) continue;
        int kloc = (c & 15) * 64;
        #pragma unroll
        for (int t = 0; t < 4; ++t) {
            int p = t * 256 + tid;
            int row = p >> 3, kgs = p & 7, kg = kgs ^ (row & 7);
            int m = row & 63;
            int src = (row >> 6) ? s1[side] : s0[side];
            s8v va = (s8v){0,0,0,0,0,0,0,0};
            if (src >= 0)
                va = *(const s8v*)(hw + (size_t)(m * L_ + src) * 1024 + kloc + kg * 8);
            *(s8v*)(lA + (size_t)p * 8) = va;
            *(s8v*)(lB + (size_t)p * 8) = *(const s8v*)(wrt + (size_t)(cb + row) * 2048 + side * 1024 + kloc + kg * 8);
        }
        __syncthreads();
        #pragma unroll
        for (int s = 0; s < 2; ++s) {
            int kgx = (s * 4 + lq) ^ (lr & 7);
            s8v a[4], b[4];
            #pragma unroll
            for (int i = 0; i < 4; ++i) {
                int rowa = wr * 64 + i * 16 + lr;
                int rowb = wc * 64 + i * 16 + lr;
                a[i] = *(const s8v*)(lA + (size_t)(rowa * 8 + kgx) * 8);
                b[i] = *(const s8v*)(lB + (size_t)(rowb * 8 + kgx) * 8);
            }
            #pragma unroll
            for (int i = 0; i < 4; ++i)
                #pragma unroll
                for (int j = 0; j < 4; ++j)
                    acc[i][j] = __builtin_amdgcn_mfma_f32_16x16x32_bf16(a[i], b[j], acc[i][j], 0, 0, 0);
        }
        __syncthreads();
    }
    #pragma unroll
    for (int j = 0; j < 4; ++j) {
        int col = cb + wc * 64 + j * 16 + lr;
        float bias = br[col];
        #pragma unroll
        for (int i = 0; i < 4; ++i) {
            #pragma unroll
            for (int jj = 0; jj < 4; ++jj) {
                int prow = wr * 64 + i * 16 + lq * 4 + jj;
                int rr = r0 + (prow >> 6), m = prow & 63;
                if (rr < nred)
                    pwb[((size_t)rr * B_ + m) * 5120 + col] = f2bf(acc[i][j][jj] + bias);
            }
        }
    }
}

// ---------------- one reduce step (round-8/14 proven config) ----------------
// 256 blocks x 512 thr (8 waves = K-split 8 -> 2 waves/SIMD).
// cg = (bid&7)*8 + ((bid>>3)&7), rh = bid>>6. Block: 16 rows x 16 ch x 5 gates.
__global__ __launch_bounds__(512) void k_step(const int* __restrict__ desc,
                                              const float* __restrict__ cw,
                                              const unsigned short* __restrict__ bpk,
                                              const unsigned short* __restrict__ pwb,
                                              unsigned short* __restrict__ hpk,
                                              float* __restrict__ nc,
                                              int r) {
    int nred = desc[0];
    if (r >= nred) return;
    int ls = desc[2 + r], rs = desc[2 + RMAX + r];
    __shared__ float scr[8 * 5 * 16 * 17];    // 43520 B
    int tid = threadIdx.x, kq = tid >> 6, lane = tid & 63;
    int bid = blockIdx.x;
    int cg = (bid & 7) * 8 + ((bid >> 3) & 7);
    int rh = bid >> 6;
    int lq = lane >> 4;

    // epilogue prefetch (waves 0-3 only)
    int m_e = (tid & 255) >> 4, ci_e = tid & 15;
    int mg_e = rh * 16 + m_e, chh_e = cg * 16 + ci_e;
    float pw_pre[5] = {0.f, 0.f, 0.f, 0.f, 0.f};
    float lc = 0.f, rc = 0.f;
    if (tid < 256) {
        #pragma unroll
        for (int g = 0; g < 5; ++g)
            pw_pre[g] = bf2f(__builtin_nontemporal_load(&pwb[((size_t)r * B_ + mg_e) * 5120 + g * 1024 + chh_e]));
        lc = (ls >= 0) ? __builtin_nontemporal_load(&cw[(size_t)(mg_e * L_ + ls) * 1024 + chh_e])
                       : __builtin_nontemporal_load(&nc[((size_t)(-1 - ls) * B_ + mg_e) * 1024 + chh_e]);
        rc = (rs >= 0) ? __builtin_nontemporal_load(&cw[(size_t)(mg_e * L_ + rs) * 1024 + chh_e])
                       : __builtin_nontemporal_load(&nc[((size_t)(-1 - rs) * B_ + mg_e) * 1024 + chh_e]);
    }

    f4v acc[5];
    #pragma unroll
    for (int g = 0; g < 5; ++g) acc[g] = (f4v){0.f, 0.f, 0.f, 0.f};

    #pragma unroll
    for (int side = 0; side < 2; ++side) {
        int src = side ? rs : ls;
        if (src >= 0) continue;                 // word side fully handled by PW
        const unsigned short* A = hpk + (size_t)(-1 - src) * 65536;
        const unsigned short* Bb = bpk + (size_t)side * BPK_HALF;
        #pragma unroll
        for (int kki = 0; kki < 4; ++kki) {
            int kk = kq * 4 + kki;
            s8v a = *(const s8v*)(A + (size_t)((rh * 32 + kk) * 64 + lane) * 8);
            #pragma unroll
            for (int g = 0; g < 5; ++g) {
                s8v b = *(const s8v*)(Bb + (size_t)((((size_t)cg * 5 + g) * 32 + kk) * 64 + lane) * 8);
                acc[g] = __builtin_amdgcn_mfma_f32_16x16x32_bf16(a, b, acc[g], 0, 0, 0);
            }
        }
    }
    // write K-split partials
    #pragma unroll
    for (int g = 0; g < 5; ++g)
        #pragma unroll
        for (int jj = 0; jj < 4; ++jj)
            scr[((kq * 5 + g) * 16 + lq * 4 + jj) * 17 + (lane & 15)] = acc[g][jj];
    __syncthreads();
    if (tid < 256) {
        float gg[5];
        #pragma unroll
        for (int g = 0; g < 5; ++g) {
            float s = pw_pre[g];
            #pragma unroll
            for (int q = 0; q < 8; ++q) s += scr[((q * 5 + g) * 16 + m_e) * 17 + ci_e];
            gg[g] = s;
        }
        float cn = sigf(gg[1]) * lc + sigf(gg[2]) * rc + sigf(gg[0]) * tanhf(gg[4]);
        float hn = sigf(gg[3]) * tanhf(cn);
        unsigned short hb = f2bf(hn);
        __builtin_nontemporal_store(cn, &nc[((size_t)r * B_ + mg_e) * 1024 + chh_e]);
        // packed-A write for future steps (also serves k_final)
        int rf = mg_e >> 4, lr2 = mg_e & 15, kk2 = chh_e >> 5, lq2 = (chh_e >> 3) & 3, j = chh_e & 7;
        __builtin_nontemporal_store(hb, &hpk[(size_t)r * 65536 + (size_t)((rf * 32 + kk2) * 64 + lq2 * 16 + lr2) * 8 + j]);
    }
}

// ---------------- final: read from hw (word) or fragment-packed hpk (node) ----------------
__global__ void k_final(const int* __restrict__ desc,
                        const unsigned short* __restrict__ hw,
                        const unsigned short* __restrict__ hpk,
                        float* __restrict__ out) {
    int idx = blockIdx.x * 256 + threadIdx.x;
    if (idx >= B_ * 1024) return;
    int m = idx >> 10, ch = idx & 1023;
    int fs = desc[1];
    unsigned short v;
    if (fs >= 0) {
        v = hw[((size_t)(m * L_ + fs) << 10) + ch];
    } else {
        int r = -1 - fs;
        int rf = m >> 4, lr2 = m & 15, kk2 = ch >> 5, lq2 = (ch >> 3) & 3, j = ch & 7;
        v = hpk[(size_t)r * 65536 + (size_t)((rf * 32 + kk2) * 64 + lq2 * 16 + lr2) * 8 + j];
    }
    out[idx] = bf2f(v);
}

extern "C" void kernel_launch(void* const* d_in, const int* in_sizes, int n_in,
                              void* d_out, int out_size, void* d_ws, size_t ws_size,
                              hipStream_t stream) {
    const float* sentence = (const float*)d_in[0];
    const int*   trans    = (const int*)d_in[1];
    const float* Ww       = (const float*)d_in[2];
    const float* bw       = (const float*)d_in[3];
    const float* Wr       = (const float*)d_in[4];
    const float* br       = (const float*)d_in[5];
    float* out = (float*)d_out;

    char* w = (char*)d_ws;
    size_t off = 0;
    unsigned short* Wrt = (unsigned short*)(w + off); off += (size_t)5120 * 2048 * 2;      // 21.0 MB
    unsigned short* Wwt = (unsigned short*)(w + off); off += (size_t)2048 * 1024 * 2;      //  4.2 MB
    unsigned short* bpk = (unsigned short*)(w + off); off += (size_t)2 * BPK_HALF * 2;     // 21.0 MB
    unsigned short* sb  = (unsigned short*)(w + off); off += (size_t)8192 * 1024 * 2;      // 16.8 MB
    unsigned short* hw  = (unsigned short*)(w + off); off += (size_t)8192 * 1024 * 2;      // 16.8 MB
    float*          cw  = (float*)(w + off);          off += (size_t)8192 * 1024 * 4;      // 33.6 MB
    float*          nc  = (float*)(w + off);          off += (size_t)RMAX * B_ * 1024 * 4; // 33.3 MB
    unsigned short* hpk = (unsigned short*)(w + off); off += (size_t)RMAX * 65536 * 2;     // 16.6 MB
    unsigned short* pwb = (unsigned short*)(w + off); off += (size_t)RMAX * B_ * 5120 * 2; // 83.2 MB
    int*            desc = (int*)(w + off);           off += 1024;                         // ~246.5 MB

    {
        long n4 = (long)8192 * 1024 / 4;
        k_cvt_bf16<<<dim3((unsigned)((n4 + 255) / 256)), dim3(256), 0, stream>>>(sentence, sb, n4);
    }
    k_transpose_bf16<<<dim3(2048 / 32, 1024 / 32), dim3(32, 8), 0, stream>>>(Ww, Wwt, 1024, 2048);
    k_transpose_bf16<<<dim3(5120 / 32, 2048 / 32), dim3(32, 8), 0, stream>>>(Wr, Wrt, 2048, 5120);
    k_pack_b<<<dim3(5120), dim3(256), 0, stream>>>(Wrt, bpk);
    k_control<<<dim3(1), dim3(1), 0, stream>>>(trans, desc);
    k_proj2<<<dim3(16, 64), dim3(256), 0, stream>>>(sb, Wwt, bw, hw, cw);
    k_pw<<<dim3(40, 64), dim3(256), 0, stream>>>(desc, hw, Wrt, br, pwb);
    for (int r = 0; r < RMAX; ++r)
        k_step<<<dim3(256), dim3(512), 0, stream>>>(desc, cw, bpk, pwb, hpk, nc, r);
    k_final<<<dim3((B_ * 1024 + 255) / 256), dim3(256), 0, stream>>>(desc, hw, hpk, out);
}